// Round 7
// baseline (103.059 us; speedup 1.0000x reference)
//
#include <hip/hip_runtime.h>

#define BATCH   16384
#define NF      1024
#define NWAVES  4096
#define NROWS   (BATCH / NWAVES)   // 4 rows per wave

// 4096 waves (1024 blocks): 4 blocks/CU x 4 waves/SIMD residency at ~116 VGPR.
// Each wave: 4 rows, x prefetched two rows ahead (3 rolling buffers, static).
// Lane l owns columns {4*l + 256*k + j : k in 0..3, j in 0..3}.
// Leaf values in LDS, transposed (lv_t[i*64+lane]) -> conflict-free.
// Reductions: DPP quad_perm/row_ror (full permutations) + readlane. Pure VALU.

template <int CTRL>
__device__ __forceinline__ float dpp_add(float x) {
    int xi = __builtin_bit_cast(int, x);
    int yi = __builtin_amdgcn_update_dpp(xi, xi, CTRL, 0xf, 0xf, false);
    return x + __builtin_bit_cast(float, yi);
}

__device__ __forceinline__ float row_reduce_dpp(float x) {
    x = dpp_add<0xB1>(x);    // quad_perm [1,0,3,2]
    x = dpp_add<0x4E>(x);    // quad_perm [2,3,0,1] -> quad sums
    x = dpp_add<0x124>(x);   // row_ror:4
    x = dpp_add<0x128>(x);   // row_ror:8 -> 16-lane row sum in every lane
    return x;
}

__device__ __forceinline__ float wave_sum(float x) {
    float r = row_reduce_dpp(x);
    int ri = __builtin_bit_cast(int, r);
    float s0 = __builtin_bit_cast(float, __builtin_amdgcn_readlane(ri, 0));
    float s1 = __builtin_bit_cast(float, __builtin_amdgcn_readlane(ri, 16));
    float s2 = __builtin_bit_cast(float, __builtin_amdgcn_readlane(ri, 32));
    float s3 = __builtin_bit_cast(float, __builtin_amdgcn_readlane(ri, 48));
    return (s0 + s1) + (s2 + s3);
}

__global__ __launch_bounds__(256, 4)
void sdt_kernel(const float* __restrict__ x,
                const float* __restrict__ W,
                const float* __restrict__ b,
                const float* __restrict__ leaf,
                float* __restrict__ out)
{
    const int lane = threadIdx.x & 63;
    const int wid  = (int)((blockIdx.x * blockDim.x + threadIdx.x) >> 6);

    // ---- leaf table, transposed: lv_t[i*64 + l] = leaf[l*16 + i] ----
    __shared__ float lv_t[1024];
    {
        const int t = threadIdx.x * 4;
#pragma unroll
        for (int e = 0; e < 4; ++e) {
            int idx = t + e;
            lv_t[idx] = leaf[(idx & 63) * 16 + (idx >> 6)];
        }
    }

    // ---- W slices (compiler chooses reg vs reload; VGPR ~116 observed) ----
    float4 Wr[10][4];
#pragma unroll
    for (int d = 0; d < 10; ++d)
#pragma unroll
        for (int k = 0; k < 4; ++k)
            Wr[d][k] = *reinterpret_cast<const float4*>(W + d * NF + k * 256 + 4 * lane);

    float bias[10];
#pragma unroll
    for (int d = 0; d < 10; ++d) bias[d] = b[d];

    __syncthreads();

    auto load_row = [&](float4 (&dst)[4], int r) {
        const float* xr = x + (size_t)r * NF;
#pragma unroll
        for (int k = 0; k < 4; ++k)
            dst[k] = *reinterpret_cast<const float4*>(xr + k * 256 + 4 * lane);
    };

    auto process_row = [&](const float4 (&xv)[4], int row) {
        // 10 partial dots
        float acc[10];
#pragma unroll
        for (int d = 0; d < 10; ++d) {
            float a = 0.0f;
#pragma unroll
            for (int k = 0; k < 4; ++k) {
                a = fmaf(xv[k].x, Wr[d][k].x, a);
                a = fmaf(xv[k].y, Wr[d][k].y, a);
                a = fmaf(xv[k].z, Wr[d][k].z, a);
                a = fmaf(xv[k].w, Wr[d][k].w, a);
            }
            acc[d] = a;
        }
        // gates (wave-uniform after DPP reduce)
        float g[10];
#pragma unroll
        for (int d = 0; d < 10; ++d) {
            float z = wave_sum(acc[d]) + bias[d];
            g[d] = __builtin_amdgcn_rcpf(1.0f + __expf(-z));
        }
        // leaf DP: contract LSB (depth 9) upward; leaves from LDS
        float s9[8];
#pragma unroll
        for (int j = 0; j < 8; ++j) {
            float La = lv_t[(2 * j) * 64 + lane];
            float Lb = lv_t[(2 * j + 1) * 64 + lane];
            s9[j] = fmaf(g[9], Lb - La, La);
        }
        float s8[4];
#pragma unroll
        for (int j = 0; j < 4; ++j)
            s8[j] = fmaf(g[8], s9[2 * j + 1] - s9[2 * j], s9[2 * j]);
        float s7[2];
#pragma unroll
        for (int j = 0; j < 2; ++j)
            s7[j] = fmaf(g[7], s8[2 * j + 1] - s8[2 * j], s8[2 * j]);
        float s6 = fmaf(g[6], s7[1] - s7[0], s7[0]);

        // per-lane 6-bit path weight (lane bits d=0..5, d=0 MSB)
        float w = 1.0f;
#pragma unroll
        for (int d = 0; d < 6; ++d) {
            int bit = (lane >> (5 - d)) & 1;
            w *= bit ? g[d] : (1.0f - g[d]);
        }

        float v = wave_sum(w * s6);
        if (lane == 0) out[row] = v;
    };

    // ---- 3-stage rolling pipeline over 4 rows: prefetch 2 ahead ----
    float4 xb0[4], xb1[4], xb2[4];
    load_row(xb0, wid);
    load_row(xb1, wid + 1 * NWAVES);

    load_row(xb2, wid + 2 * NWAVES); process_row(xb0, wid);
    load_row(xb0, wid + 3 * NWAVES); process_row(xb1, wid + 1 * NWAVES);
    process_row(xb2, wid + 2 * NWAVES);
    process_row(xb0, wid + 3 * NWAVES);
}

extern "C" void kernel_launch(void* const* d_in, const int* in_sizes, int n_in,
                              void* d_out, int out_size, void* d_ws, size_t ws_size,
                              hipStream_t stream) {
    const float* x    = (const float*)d_in[0];
    const float* W    = (const float*)d_in[1];
    const float* b    = (const float*)d_in[2];
    const float* leaf = (const float*)d_in[3];
    float* out = (float*)d_out;

    const int blocks  = 1024;  // 4096 waves = 4 blocks/CU x 4 waves/SIMD
    const int threads = 256;

    sdt_kernel<<<blocks, threads, 0, stream>>>(x, W, b, leaf, out);
}

// Round 8
// 26.266 us; speedup vs baseline: 3.9236x; 3.9236x over previous
//
#include <hip/hip_runtime.h>

#define BATCH   16384
#define NF      1024
#define NWAVES  4096
#define NROWS   (BATCH / NWAVES)   // 4 rows per wave

// 4096 waves (1024 blocks) at VGPR<=128 -> 4 blocks/CU x 4 waves/SIMD.
// NOTE: launch_bounds(256,2) on purpose — (256,4) made the allocator cap at
// 64 VGPR and spill Wr + x-buffers to scratch (R7: FETCH 33->224 MB, 4x dur).
// Each wave: 4 rows, x prefetched two rows ahead (3 rolling buffers, static).
// Lane l owns columns {4*l + 256*k + j : k in 0..3, j in 0..3}.
// Leaf values in LDS, transposed (lv_t[i*64+lane]) -> conflict-free.
// Reductions: DPP quad_perm/row_ror (full permutations) + readlane. Pure VALU.

template <int CTRL>
__device__ __forceinline__ float dpp_add(float x) {
    int xi = __builtin_bit_cast(int, x);
    int yi = __builtin_amdgcn_update_dpp(xi, xi, CTRL, 0xf, 0xf, false);
    return x + __builtin_bit_cast(float, yi);
}

__device__ __forceinline__ float row_reduce_dpp(float x) {
    x = dpp_add<0xB1>(x);    // quad_perm [1,0,3,2]
    x = dpp_add<0x4E>(x);    // quad_perm [2,3,0,1] -> quad sums
    x = dpp_add<0x124>(x);   // row_ror:4
    x = dpp_add<0x128>(x);   // row_ror:8 -> 16-lane row sum in every lane
    return x;
}

__device__ __forceinline__ float wave_sum(float x) {
    float r = row_reduce_dpp(x);
    int ri = __builtin_bit_cast(int, r);
    float s0 = __builtin_bit_cast(float, __builtin_amdgcn_readlane(ri, 0));
    float s1 = __builtin_bit_cast(float, __builtin_amdgcn_readlane(ri, 16));
    float s2 = __builtin_bit_cast(float, __builtin_amdgcn_readlane(ri, 32));
    float s3 = __builtin_bit_cast(float, __builtin_amdgcn_readlane(ri, 48));
    return (s0 + s1) + (s2 + s3);
}

__global__ __launch_bounds__(256, 2)
void sdt_kernel(const float* __restrict__ x,
                const float* __restrict__ W,
                const float* __restrict__ b,
                const float* __restrict__ leaf,
                float* __restrict__ out)
{
    const int lane = threadIdx.x & 63;
    const int wid  = (int)((blockIdx.x * blockDim.x + threadIdx.x) >> 6);

    // ---- leaf table, transposed: lv_t[i*64 + l] = leaf[l*16 + i] ----
    __shared__ float lv_t[1024];
    {
        const int t = threadIdx.x * 4;
#pragma unroll
        for (int e = 0; e < 4; ++e) {
            int idx = t + e;
            lv_t[idx] = leaf[(idx & 63) * 16 + (idx >> 6)];
        }
    }

    // ---- W slices (compiler chooses reg vs reload; VGPR ~116 observed) ----
    float4 Wr[10][4];
#pragma unroll
    for (int d = 0; d < 10; ++d)
#pragma unroll
        for (int k = 0; k < 4; ++k)
            Wr[d][k] = *reinterpret_cast<const float4*>(W + d * NF + k * 256 + 4 * lane);

    float bias[10];
#pragma unroll
    for (int d = 0; d < 10; ++d) bias[d] = b[d];

    __syncthreads();

    auto load_row = [&](float4 (&dst)[4], int r) {
        const float* xr = x + (size_t)r * NF;
#pragma unroll
        for (int k = 0; k < 4; ++k)
            dst[k] = *reinterpret_cast<const float4*>(xr + k * 256 + 4 * lane);
    };

    auto process_row = [&](const float4 (&xv)[4], int row) {
        // 10 partial dots
        float acc[10];
#pragma unroll
        for (int d = 0; d < 10; ++d) {
            float a = 0.0f;
#pragma unroll
            for (int k = 0; k < 4; ++k) {
                a = fmaf(xv[k].x, Wr[d][k].x, a);
                a = fmaf(xv[k].y, Wr[d][k].y, a);
                a = fmaf(xv[k].z, Wr[d][k].z, a);
                a = fmaf(xv[k].w, Wr[d][k].w, a);
            }
            acc[d] = a;
        }
        // gates (wave-uniform after DPP reduce)
        float g[10];
#pragma unroll
        for (int d = 0; d < 10; ++d) {
            float z = wave_sum(acc[d]) + bias[d];
            g[d] = __builtin_amdgcn_rcpf(1.0f + __expf(-z));
        }
        // leaf DP: contract LSB (depth 9) upward; leaves from LDS
        float s9[8];
#pragma unroll
        for (int j = 0; j < 8; ++j) {
            float La = lv_t[(2 * j) * 64 + lane];
            float Lb = lv_t[(2 * j + 1) * 64 + lane];
            s9[j] = fmaf(g[9], Lb - La, La);
        }
        float s8[4];
#pragma unroll
        for (int j = 0; j < 4; ++j)
            s8[j] = fmaf(g[8], s9[2 * j + 1] - s9[2 * j], s9[2 * j]);
        float s7[2];
#pragma unroll
        for (int j = 0; j < 2; ++j)
            s7[j] = fmaf(g[7], s8[2 * j + 1] - s8[2 * j], s8[2 * j]);
        float s6 = fmaf(g[6], s7[1] - s7[0], s7[0]);

        // per-lane 6-bit path weight (lane bits d=0..5, d=0 MSB)
        float w = 1.0f;
#pragma unroll
        for (int d = 0; d < 6; ++d) {
            int bit = (lane >> (5 - d)) & 1;
            w *= bit ? g[d] : (1.0f - g[d]);
        }

        float v = wave_sum(w * s6);
        if (lane == 0) out[row] = v;
    };

    // ---- 3-stage rolling pipeline over 4 rows: prefetch 2 ahead ----
    float4 xb0[4], xb1[4], xb2[4];
    load_row(xb0, wid);
    load_row(xb1, wid + 1 * NWAVES);

    load_row(xb2, wid + 2 * NWAVES); process_row(xb0, wid);
    load_row(xb0, wid + 3 * NWAVES); process_row(xb1, wid + 1 * NWAVES);
    process_row(xb2, wid + 2 * NWAVES);
    process_row(xb0, wid + 3 * NWAVES);
}

extern "C" void kernel_launch(void* const* d_in, const int* in_sizes, int n_in,
                              void* d_out, int out_size, void* d_ws, size_t ws_size,
                              hipStream_t stream) {
    const float* x    = (const float*)d_in[0];
    const float* W    = (const float*)d_in[1];
    const float* b    = (const float*)d_in[2];
    const float* leaf = (const float*)d_in[3];
    float* out = (float*)d_out;

    const int blocks  = 1024;  // 4 blocks/CU; residency set by VGPR (~116 -> 4 waves/SIMD)
    const int threads = 256;

    sdt_kernel<<<blocks, threads, 0, stream>>>(x, W, b, leaf, out);
}

// Round 9
// 25.717 us; speedup vs baseline: 4.0074x; 1.0213x over previous
//
#include <hip/hip_runtime.h>

#define BATCH   16384
#define NF      1024
#define NWAVES  2048
#define NROWS   (BATCH / NWAVES)   // 8 rows per wave

// KEY FIX (R8 diagnosis): in all prior rounds VGPR_Count was ~112-116,
// proving Wr[10][4] (160 VGPRs) was NEVER resident — the compiler
// rematerialized the W global loads inside every row ⇒ 655 MB/launch of
// L1/L2 traffic (~25 TB/s) ⇒ the 26-µs L2-bound plateau no amount of
// occupancy/prefetch/compute restructuring could move.
// The empty asm with "+v" below redefines each W value as asm output, so
// the compiler cannot re-load it from memory — W stays in VGPRs for the
// whole kernel (~240 VGPR -> 2 waves/SIMD, fine: W traffic becomes 0).

template <int CTRL>
__device__ __forceinline__ float dpp_add(float x) {
    int xi = __builtin_bit_cast(int, x);
    int yi = __builtin_amdgcn_update_dpp(xi, xi, CTRL, 0xf, 0xf, false);
    return x + __builtin_bit_cast(float, yi);
}

__device__ __forceinline__ float row_reduce_dpp(float x) {
    x = dpp_add<0xB1>(x);    // quad_perm [1,0,3,2]
    x = dpp_add<0x4E>(x);    // quad_perm [2,3,0,1] -> quad sums
    x = dpp_add<0x124>(x);   // row_ror:4
    x = dpp_add<0x128>(x);   // row_ror:8 -> 16-lane row sum in every lane
    return x;
}

__device__ __forceinline__ float wave_sum(float x) {
    float r = row_reduce_dpp(x);
    int ri = __builtin_bit_cast(int, r);
    float s0 = __builtin_bit_cast(float, __builtin_amdgcn_readlane(ri, 0));
    float s1 = __builtin_bit_cast(float, __builtin_amdgcn_readlane(ri, 16));
    float s2 = __builtin_bit_cast(float, __builtin_amdgcn_readlane(ri, 32));
    float s3 = __builtin_bit_cast(float, __builtin_amdgcn_readlane(ri, 48));
    return (s0 + s1) + (s2 + s3);
}

__global__ __launch_bounds__(256, 2)
void sdt_kernel(const float* __restrict__ x,
                const float* __restrict__ W,
                const float* __restrict__ b,
                const float* __restrict__ leaf,
                float* __restrict__ out)
{
    const int lane = threadIdx.x & 63;
    const int wid  = (int)((blockIdx.x * blockDim.x + threadIdx.x) >> 6);

    // ---- leaf table, transposed: lv_t[i*64 + l] = leaf[l*16 + i] ----
    __shared__ float lv_t[1024];
    {
        const int t = threadIdx.x * 4;
#pragma unroll
        for (int e = 0; e < 4; ++e) {
            int idx = t + e;
            lv_t[idx] = leaf[(idx & 63) * 16 + (idx >> 6)];
        }
    }

    // ---- W slices: Wr[d][k] = W[d][256k + 4l .. +3], PINNED in VGPRs ----
    float4 Wr[10][4];
#pragma unroll
    for (int d = 0; d < 10; ++d)
#pragma unroll
        for (int k = 0; k < 4; ++k)
            Wr[d][k] = *reinterpret_cast<const float4*>(W + d * NF + k * 256 + 4 * lane);

    // Pin: values become asm-defined -> cannot be rematerialized from memory.
#pragma unroll
    for (int d = 0; d < 10; ++d)
#pragma unroll
        for (int k = 0; k < 4; ++k)
            asm volatile("" : "+v"(Wr[d][k].x), "+v"(Wr[d][k].y),
                              "+v"(Wr[d][k].z), "+v"(Wr[d][k].w));

    float bias[10];
#pragma unroll
    for (int d = 0; d < 10; ++d) bias[d] = b[d];

    __syncthreads();

    auto load_row = [&](float4 (&dst)[4], int r) {
        const float* xr = x + (size_t)r * NF;
#pragma unroll
        for (int k = 0; k < 4; ++k)
            dst[k] = *reinterpret_cast<const float4*>(xr + k * 256 + 4 * lane);
    };

    auto process_row = [&](const float4 (&xv)[4], int row) {
        // 10 partial dots
        float acc[10];
#pragma unroll
        for (int d = 0; d < 10; ++d) {
            float a = 0.0f;
#pragma unroll
            for (int k = 0; k < 4; ++k) {
                a = fmaf(xv[k].x, Wr[d][k].x, a);
                a = fmaf(xv[k].y, Wr[d][k].y, a);
                a = fmaf(xv[k].z, Wr[d][k].z, a);
                a = fmaf(xv[k].w, Wr[d][k].w, a);
            }
            acc[d] = a;
        }
        // gates (wave-uniform after DPP reduce)
        float g[10];
#pragma unroll
        for (int d = 0; d < 10; ++d) {
            float z = wave_sum(acc[d]) + bias[d];
            g[d] = __builtin_amdgcn_rcpf(1.0f + __expf(-z));
        }
        // leaf DP: contract LSB (depth 9) upward; leaves from LDS
        float s9[8];
#pragma unroll
        for (int j = 0; j < 8; ++j) {
            float La = lv_t[(2 * j) * 64 + lane];
            float Lb = lv_t[(2 * j + 1) * 64 + lane];
            s9[j] = fmaf(g[9], Lb - La, La);
        }
        float s8[4];
#pragma unroll
        for (int j = 0; j < 4; ++j)
            s8[j] = fmaf(g[8], s9[2 * j + 1] - s9[2 * j], s9[2 * j]);
        float s7[2];
#pragma unroll
        for (int j = 0; j < 2; ++j)
            s7[j] = fmaf(g[7], s8[2 * j + 1] - s8[2 * j], s8[2 * j]);
        float s6 = fmaf(g[6], s7[1] - s7[0], s7[0]);

        // per-lane 6-bit path weight (lane bits d=0..5, d=0 MSB)
        float w = 1.0f;
#pragma unroll
        for (int d = 0; d < 6; ++d) {
            int bit = (lane >> (5 - d)) & 1;
            w *= bit ? g[d] : (1.0f - g[d]);
        }

        float v = wave_sum(w * s6);
        if (lane == 0) out[row] = v;
    };

    // ---- double-buffered pipeline over 8 rows (depth 1, regs tight) ----
    float4 xa[4], xb[4];
    load_row(xa, wid);

    load_row(xb, wid + 1 * NWAVES); process_row(xa, wid);
    load_row(xa, wid + 2 * NWAVES); process_row(xb, wid + 1 * NWAVES);
    load_row(xb, wid + 3 * NWAVES); process_row(xa, wid + 2 * NWAVES);
    load_row(xa, wid + 4 * NWAVES); process_row(xb, wid + 3 * NWAVES);
    load_row(xb, wid + 5 * NWAVES); process_row(xa, wid + 4 * NWAVES);
    load_row(xa, wid + 6 * NWAVES); process_row(xb, wid + 5 * NWAVES);
    load_row(xb, wid + 7 * NWAVES); process_row(xa, wid + 6 * NWAVES);
    process_row(xb, wid + 7 * NWAVES);
}

extern "C" void kernel_launch(void* const* d_in, const int* in_sizes, int n_in,
                              void* d_out, int out_size, void* d_ws, size_t ws_size,
                              hipStream_t stream) {
    const float* x    = (const float*)d_in[0];
    const float* W    = (const float*)d_in[1];
    const float* b    = (const float*)d_in[2];
    const float* leaf = (const float*)d_in[3];
    float* out = (float*)d_out;

    const int blocks  = 512;   // 2048 waves = exact residency at 2 waves/SIMD
    const int threads = 256;

    sdt_kernel<<<blocks, threads, 0, stream>>>(x, W, b, leaf, out);
}